// Round 3
// baseline (22.567 us; speedup 1.0000x reference)
//
#include <hip/hip_runtime.h>
#include <hip/hip_fp16.h>

// bg: (1, 4, 32, 32, 32, 16) f32 ; gm: (1,1,128,128,128) f32 ; out: (1,4,128,128,128) f32
//
// Tile: 8(i) x 8(j) x 32(k) voxels per 512-thread block; each thread does 4
// consecutive k. Grid nodes needed: 4(x) x 4(y) x 10(z) = 160.
// LDS: fp16, per node 16 t-slots; slot s = {t=s: c0..c3, t=s+1: c0..c3} (16B)
// -> one ds_read_b128 per corner. Node stride 68 dwords (64+4 pad).

#define S_ (31.0f / 127.0f)
#define CH_STRIDE 524288
#define TOTAL 2097152

#define NX 4
#define NY 4
#define NZ 10
#define NNODES (NX * NY * NZ)          // 160
#define NODE_DW 68                     // dwords per node (16 slots * 4 + pad)
#define LDS_DW (NNODES * NODE_DW)      // 10880 dwords = 43520 B

__global__ __launch_bounds__(512) void bgrid_slice_f16(
    const float* __restrict__ bg,
    const float* __restrict__ gm,
    float* __restrict__ out)
{
    __shared__ __align__(16) float lds[LDS_DW];

    const int tid = threadIdx.x;
    const int b = blockIdx.x;
    const int bk = b & 3;
    const int bj = (b >> 2) & 15;
    const int bi = b >> 6;

    const int i0 = bi * 8, j0 = bj * 8, k0 = bk * 32;
    const int x_base = (int)((float)i0 * S_);
    const int y_base = (int)((float)j0 * S_);
    const int z_base = (int)((float)k0 * S_);

    // ---- stage: 160 nodes * 16 slots; item q = (node, s) ----
    for (int q = tid; q < NNODES * 16; q += 512) {
        const int node = q >> 4;
        const int s = q & 15;
        const int s2 = min(s + 1, 15);
        const int a = node / (NY * NZ);
        const int rem = node - a * (NY * NZ);
        const int bb = rem / NZ;
        const int cz = rem - bb * NZ;
        const int gx = min(x_base + a, 31);
        const int gy = min(y_base + bb, 31);
        const int gz = min(z_base + cz, 31);
        const int gbase = ((gx * 32 + gy) * 32 + gz) << 4;

        const float c0a = bg[gbase + s];
        const float c0b = bg[gbase + s2];
        const float c1a = bg[CH_STRIDE + gbase + s];
        const float c1b = bg[CH_STRIDE + gbase + s2];
        const float c2a = bg[2 * CH_STRIDE + gbase + s];
        const float c2b = bg[2 * CH_STRIDE + gbase + s2];
        const float c3a = bg[3 * CH_STRIDE + gbase + s];
        const float c3b = bg[3 * CH_STRIDE + gbase + s2];

        float4 slot;
        slot.x = __builtin_bit_cast(float, __floats2half2_rn(c0a, c1a));
        slot.y = __builtin_bit_cast(float, __floats2half2_rn(c2a, c3a));
        slot.z = __builtin_bit_cast(float, __floats2half2_rn(c0b, c1b));
        slot.w = __builtin_bit_cast(float, __floats2half2_rn(c2b, c3b));
        *(float4*)&lds[node * NODE_DW + (s << 2)] = slot;
    }
    __syncthreads();

    // ---- interp: thread = (li, lj, kq); 4 voxels k = kq*4 .. kq*4+3 ----
    const int li = tid >> 6;
    const int lj = (tid >> 3) & 7;
    const int kq = tid & 7;
    const int i = i0 + li, j = j0 + lj;
    const int kk = k0 + (kq << 2);

    float xf = fminf((float)i * S_, 31.0f);
    float yf = fminf((float)j * S_, 31.0f);
    int x0g = (int)xf; float fx = xf - (float)x0g;
    int y0g = (int)yf; float fy = yf - (float)y0g;
    const int xi0 = x0g - x_base, xi1 = min(x0g + 1, 31) - x_base;
    const int yi0 = y0g - y_base, yi1 = min(y0g + 1, 31) - y_base;

    const int AX0 = xi0 * (NY * NZ * NODE_DW);
    const int AX1 = xi1 * (NY * NZ * NODE_DW);
    const int BY0 = yi0 * (NZ * NODE_DW);
    const int BY1 = yi1 * (NZ * NODE_DW);

    const float wx1 = fx, wx0 = 1.0f - fx;
    const float wy1 = fy, wy0 = 1.0f - fy;
    const float w00 = wx0 * wy0, w01 = wx0 * wy1;
    const float w10 = wx1 * wy0, w11 = wx1 * wy1;

    const int idx = (i << 14) | (j << 7) | kk;
    const float4 g4 = *(const float4*)&gm[idx];

    float o0[4], o1[4], o2[4], o3[4];

#pragma unroll
    for (int v = 0; v < 4; ++v) {
        const float g = (v == 0) ? g4.x : (v == 1) ? g4.y : (v == 2) ? g4.z : g4.w;
        float t = fminf(fmaxf(g * 15.0f, 0.0f), 15.0f);
        const int t0 = min((int)t, 14);
        const float ft = t - (float)t0;
        const __half2 ft2 = __float2half2_rn(ft);

        const float zf = fminf((float)(kk + v) * S_, 31.0f);
        const int z0g = (int)zf;
        const float fz = zf - (float)z0g;
        const int zi0 = z0g - z_base;
        const int zi1 = min(z0g + 1, 31) - z_base;
        const float wz0 = 1.0f - fz, wz1 = fz;

        const int CZ0 = zi0 * NODE_DW + (t0 << 2);
        const int CZ1 = zi1 * NODE_DW + (t0 << 2);

        float a0 = 0.f, a1 = 0.f, a2 = 0.f, a3 = 0.f;

#define CORNER(AX, BY, CZ, W)                                              \
        {                                                                  \
            const float4 raw = *(const float4*)&lds[(AX) + (BY) + (CZ)];   \
            const __half2 lo01 = __builtin_bit_cast(__half2, raw.x);       \
            const __half2 lo23 = __builtin_bit_cast(__half2, raw.y);       \
            const __half2 hi01 = __builtin_bit_cast(__half2, raw.z);       \
            const __half2 hi23 = __builtin_bit_cast(__half2, raw.w);       \
            const __half2 r01 = __hfma2(ft2, __hsub2(hi01, lo01), lo01);   \
            const __half2 r23 = __hfma2(ft2, __hsub2(hi23, lo23), lo23);   \
            const float w = (W);                                           \
            a0 = fmaf(w, __low2float(r01), a0);                            \
            a1 = fmaf(w, __high2float(r01), a1);                           \
            a2 = fmaf(w, __low2float(r23), a2);                            \
            a3 = fmaf(w, __high2float(r23), a3);                           \
        }

        CORNER(AX0, BY0, CZ0, w00 * wz0)
        CORNER(AX0, BY0, CZ1, w00 * wz1)
        CORNER(AX0, BY1, CZ0, w01 * wz0)
        CORNER(AX0, BY1, CZ1, w01 * wz1)
        CORNER(AX1, BY0, CZ0, w10 * wz0)
        CORNER(AX1, BY0, CZ1, w10 * wz1)
        CORNER(AX1, BY1, CZ0, w11 * wz0)
        CORNER(AX1, BY1, CZ1, w11 * wz1)
#undef CORNER

        o0[v] = a0; o1[v] = a1; o2[v] = a2; o3[v] = a3;
    }

    float4 st;
    st.x = o0[0]; st.y = o0[1]; st.z = o0[2]; st.w = o0[3];
    *(float4*)&out[idx] = st;
    st.x = o1[0]; st.y = o1[1]; st.z = o1[2]; st.w = o1[3];
    *(float4*)&out[idx + TOTAL] = st;
    st.x = o2[0]; st.y = o2[1]; st.z = o2[2]; st.w = o2[3];
    *(float4*)&out[idx + 2 * TOTAL] = st;
    st.x = o3[0]; st.y = o3[1]; st.z = o3[2]; st.w = o3[3];
    *(float4*)&out[idx + 3 * TOTAL] = st;
}

extern "C" void kernel_launch(void* const* d_in, const int* in_sizes, int n_in,
                              void* d_out, int out_size, void* d_ws, size_t ws_size,
                              hipStream_t stream) {
    const float* bg = (const float*)d_in[0];
    const float* gm = (const float*)d_in[1];
    float* out = (float*)d_out;

    dim3 grid(1024);   // (128/8)*(128/8)*(128/32)
    dim3 block(512);
    bgrid_slice_f16<<<grid, block, 0, stream>>>(bg, gm, out);
}

// Round 4
// 19.533 us; speedup vs baseline: 1.1553x; 1.1553x over previous
//
#include <hip/hip_runtime.h>
#include <hip/hip_fp16.h>

// bg: (1,4,32,32,32,16) f32 ; gm: (1,1,128,128,128) f32 ; out: (1,4,128,128,128) f32
//
// Tile: 8(i) x 8(j) x 16(k) voxels / 256-thread block; 4 consecutive k per thread.
// Grid nodes: 4(x) x 4(y) x 6(z) = 96. LDS fp16, per node 16 t-slots of 16B:
// slot s = {t=s: c0c1, c2c3 | t=s+1: c0c1, c2c3} -> one ds_read_b128 per corner.
// Node stride 68 dwords. LDS = 96*68*4 = 26112 B -> 6 blocks/CU.

#define S_ (31.0f / 127.0f)
#define CH_STRIDE 524288
#define TOTAL 2097152

#define NX 4
#define NY 4
#define NZ 6
#define NNODES (NX * NY * NZ)          // 96
#define NODE_DW 68
#define LDS_DW (NNODES * NODE_DW)      // 6528 dwords = 26112 B

__global__ __launch_bounds__(256, 5) void bgrid_slice_v4(
    const float* __restrict__ bg,
    const float* __restrict__ gm,
    float* __restrict__ out)
{
    __shared__ __align__(16) float lds[LDS_DW];

    const int tid = threadIdx.x;
    const int b = blockIdx.x;
    const int bk = b & 7;
    const int bj = (b >> 3) & 15;
    const int bi = b >> 7;

    const int i0 = bi * 8, j0 = bj * 8, k0 = bk * 16;
    const int x_base = (int)((float)i0 * S_);
    const int y_base = (int)((float)j0 * S_);
    const int z_base = (int)((float)k0 * S_);

    // ---- stage: 96 nodes * 16 slots = 1536 items, 6 per thread ----
    // item (node, s): load v[s] for 4 channels; write as lo of slot s and
    // hi of slot s-1 (and hi of slot 15 when s==15).
    for (int q = tid; q < NNODES * 16; q += 256) {
        const int node = q >> 4;
        const int s = q & 15;
        const int a = node / (NY * NZ);
        const int rem = node - a * (NY * NZ);
        const int bb = rem / NZ;
        const int cz = rem - bb * NZ;
        const int gx = min(x_base + a, 31);
        const int gy = min(y_base + bb, 31);
        const int gz = min(z_base + cz, 31);
        const int gbase = (((gx * 32 + gy) * 32 + gz) << 4) + s;

        const float c0 = bg[gbase];
        const float c1 = bg[gbase + CH_STRIDE];
        const float c2 = bg[gbase + 2 * CH_STRIDE];
        const float c3 = bg[gbase + 3 * CH_STRIDE];

        float2 pk;
        pk.x = __builtin_bit_cast(float, __floats2half2_rn(c0, c1));
        pk.y = __builtin_bit_cast(float, __floats2half2_rn(c2, c3));

        const int nb = node * NODE_DW;
        *(float2*)&lds[nb + (s << 2)] = pk;                    // lo of slot s
        if (s > 0)  *(float2*)&lds[nb + ((s - 1) << 2) + 2] = pk;  // hi of slot s-1
        if (s == 15) *(float2*)&lds[nb + (15 << 2) + 2] = pk;      // hi of slot 15 (clamp)
    }
    __syncthreads();

    // ---- interp: thread = (li, lj, kq); voxels k = k0+kq*4 .. +3 ----
    const int kq = tid & 3;
    const int lj = (tid >> 2) & 7;
    const int li = tid >> 5;
    const int i = i0 + li, j = j0 + lj;
    const int kk = k0 + (kq << 2);

    const float xf = fminf((float)i * S_, 31.0f);
    const float yf = fminf((float)j * S_, 31.0f);
    const int x0g = (int)xf; const float fx = xf - (float)x0g;
    const int y0g = (int)yf; const float fy = yf - (float)y0g;
    const int xi0 = x0g - x_base, xi1 = min(x0g + 1, 31) - x_base;
    const int yi0 = y0g - y_base, yi1 = min(y0g + 1, 31) - y_base;

    const int AX0 = xi0 * (NY * NZ * NODE_DW);
    const int AX1 = xi1 * (NY * NZ * NODE_DW);
    const int BY0 = yi0 * (NZ * NODE_DW);
    const int BY1 = yi1 * (NZ * NODE_DW);

    const float wx1 = fx, wx0 = 1.0f - fx;
    const float wy1 = fy, wy0 = 1.0f - fy;
    const __half2 W00 = __float2half2_rn(wx0 * wy0);
    const __half2 W01 = __float2half2_rn(wx0 * wy1);
    const __half2 W10 = __float2half2_rn(wx1 * wy0);
    const __half2 W11 = __float2half2_rn(wx1 * wy1);

    const int idx = (i << 14) | (j << 7) | kk;
    const float4 g4 = *(const float4*)&gm[idx];

    float o0[4], o1[4], o2[4], o3[4];

#pragma unroll
    for (int v = 0; v < 4; ++v) {
        const float g = (v == 0) ? g4.x : (v == 1) ? g4.y : (v == 2) ? g4.z : g4.w;
        float t = fminf(fmaxf(g * 15.0f, 0.0f), 15.0f);
        const int t0 = min((int)t, 14);
        const float ft = t - (float)t0;
        const __half2 ft2 = __float2half2_rn(ft);

        const float zf = fminf((float)(kk + v) * S_, 31.0f);
        const int z0g = (int)zf;
        const float fz = zf - (float)z0g;
        const int zi0 = z0g - z_base;
        const int zi1 = min(z0g + 1, 31) - z_base;
        const __half2 fz2 = __float2half2_rn(fz);

        const int CZ0 = zi0 * NODE_DW + (t0 << 2);
        const int CZ1 = zi1 * NODE_DW + (t0 << 2);

        const float4 a00 = *(const float4*)&lds[AX0 + BY0 + CZ0];
        const float4 a01 = *(const float4*)&lds[AX0 + BY1 + CZ0];
        const float4 a10 = *(const float4*)&lds[AX1 + BY0 + CZ0];
        const float4 a11 = *(const float4*)&lds[AX1 + BY1 + CZ0];
        const float4 b00 = *(const float4*)&lds[AX0 + BY0 + CZ1];
        const float4 b01 = *(const float4*)&lds[AX0 + BY1 + CZ1];
        const float4 b10 = *(const float4*)&lds[AX1 + BY0 + CZ1];
        const float4 b11 = *(const float4*)&lds[AX1 + BY1 + CZ1];

#define H2(f) __builtin_bit_cast(__half2, f)
        // xy-accumulate (fp16), z0 plane (P) and z1 plane (Q), 4 components each
        __half2 Plo01 = __hmul2(W00, H2(a00.x));
        __half2 Plo23 = __hmul2(W00, H2(a00.y));
        __half2 Phi01 = __hmul2(W00, H2(a00.z));
        __half2 Phi23 = __hmul2(W00, H2(a00.w));
        Plo01 = __hfma2(W01, H2(a01.x), Plo01);
        Plo23 = __hfma2(W01, H2(a01.y), Plo23);
        Phi01 = __hfma2(W01, H2(a01.z), Phi01);
        Phi23 = __hfma2(W01, H2(a01.w), Phi23);
        Plo01 = __hfma2(W10, H2(a10.x), Plo01);
        Plo23 = __hfma2(W10, H2(a10.y), Plo23);
        Phi01 = __hfma2(W10, H2(a10.z), Phi01);
        Phi23 = __hfma2(W10, H2(a10.w), Phi23);
        Plo01 = __hfma2(W11, H2(a11.x), Plo01);
        Plo23 = __hfma2(W11, H2(a11.y), Plo23);
        Phi01 = __hfma2(W11, H2(a11.z), Phi01);
        Phi23 = __hfma2(W11, H2(a11.w), Phi23);

        __half2 Qlo01 = __hmul2(W00, H2(b00.x));
        __half2 Qlo23 = __hmul2(W00, H2(b00.y));
        __half2 Qhi01 = __hmul2(W00, H2(b00.z));
        __half2 Qhi23 = __hmul2(W00, H2(b00.w));
        Qlo01 = __hfma2(W01, H2(b01.x), Qlo01);
        Qlo23 = __hfma2(W01, H2(b01.y), Qlo23);
        Qhi01 = __hfma2(W01, H2(b01.z), Qhi01);
        Qhi23 = __hfma2(W01, H2(b01.w), Qhi23);
        Qlo01 = __hfma2(W10, H2(b10.x), Qlo01);
        Qlo23 = __hfma2(W10, H2(b10.y), Qlo23);
        Qhi01 = __hfma2(W10, H2(b10.z), Qhi01);
        Qhi23 = __hfma2(W10, H2(b10.w), Qhi23);
        Qlo01 = __hfma2(W11, H2(b11.x), Qlo01);
        Qlo23 = __hfma2(W11, H2(b11.y), Qlo23);
        Qhi01 = __hfma2(W11, H2(b11.z), Qhi01);
        Qhi23 = __hfma2(W11, H2(b11.w), Qhi23);
#undef H2

        // z blend: R = P + fz*(Q - P)
        const __half2 Rlo01 = __hfma2(fz2, __hsub2(Qlo01, Plo01), Plo01);
        const __half2 Rlo23 = __hfma2(fz2, __hsub2(Qlo23, Plo23), Plo23);
        const __half2 Rhi01 = __hfma2(fz2, __hsub2(Qhi01, Plo01 /*dummy*/), Phi01);
        const __half2 Rhi23 = __hfma2(fz2, __hsub2(Qhi23, Phi23), Phi23);
        // NOTE: fix the dummy above properly:
        const __half2 Rhi01f = __hfma2(fz2, __hsub2(Qhi01, Phi01), Phi01);

        // t lerp: out = Rlo + ft*(Rhi - Rlo)
        const __half2 r01 = __hfma2(ft2, __hsub2(Rhi01f, Rlo01), Rlo01);
        const __half2 r23 = __hfma2(ft2, __hsub2(Rhi23, Rlo23), Rlo23);
        (void)Rhi01;

        o0[v] = __low2float(r01);
        o1[v] = __high2float(r01);
        o2[v] = __low2float(r23);
        o3[v] = __high2float(r23);
    }

    float4 st;
    st.x = o0[0]; st.y = o0[1]; st.z = o0[2]; st.w = o0[3];
    *(float4*)&out[idx] = st;
    st.x = o1[0]; st.y = o1[1]; st.z = o1[2]; st.w = o1[3];
    *(float4*)&out[idx + TOTAL] = st;
    st.x = o2[0]; st.y = o2[1]; st.z = o2[2]; st.w = o2[3];
    *(float4*)&out[idx + 2 * TOTAL] = st;
    st.x = o3[0]; st.y = o3[1]; st.z = o3[2]; st.w = o3[3];
    *(float4*)&out[idx + 3 * TOTAL] = st;
}

extern "C" void kernel_launch(void* const* d_in, const int* in_sizes, int n_in,
                              void* d_out, int out_size, void* d_ws, size_t ws_size,
                              hipStream_t stream) {
    const float* bg = (const float*)d_in[0];
    const float* gm = (const float*)d_in[1];
    float* out = (float*)d_out;

    dim3 grid(2048);   // (128/8)*(128/8)*(128/16)
    dim3 block(256);
    bgrid_slice_v4<<<grid, block, 0, stream>>>(bg, gm, out);
}